// Round 10
// baseline (4718.563 us; speedup 1.0000x reference)
//
#include <hip/hip_runtime.h>
#include <hip/hip_bf16.h>

// Decoder_70033736728716 v6: v4 kernel (best, 1333us) + 3 ablation PROBES.
//
// R8 status: v3(ring)/v4(de-phase)/v5(reg-stream+nt) all ~1330-1470us,
// MfmaUtil ~10%, FETCH 1.9-3.3GB. All supply-side theories falsified ->
// measure, don't guess (guide common-mistake #8). Probes are 4x38-step scaled:
// visible in top-5 <=> that phase is the bottleneck; absent => <9us/step.
//   probe_load_shared  : exact weight stream, nothing else (shared bytes)
//   probe_load_distinct: same shape, per-block private bytes (from y buffer)
//   probe_skel         : full step skeleton (LDS+MFMA+gates+2 barriers), 0 loads
// decoder_main is EXACT v4 for comparability.

typedef __bf16 bf16x8 __attribute__((ext_vector_type(8)));
typedef float  f32x16 __attribute__((ext_vector_type(16)));

#define MFMA32(a,b,c) __builtin_amdgcn_mfma_f32_32x32x16_bf16((a),(b),(c),0,0,0)
#define WAITV(n) asm volatile("s_waitcnt vmcnt(" #n ")" ::: "memory")
#define LGKM0()  asm volatile("s_waitcnt lgkmcnt(0)" ::: "memory")
#define BARRIER() do { asm volatile("" ::: "memory"); __builtin_amdgcn_s_barrier(); asm volatile("" ::: "memory"); } while (0)

static constexpr int A_DIM = 21;

// ws layout (bytes)
static constexpr size_t O_W1F   = 0;
static constexpr size_t O_W2F   = O_W1F + 256*128*2;
static constexpr size_t O_ST1   = O_W2F + 256*256*2;
static constexpr size_t O_WMN   = O_ST1 + 8*16*3*1024;
static constexpr size_t O_WDF   = O_WMN + 8*16*4*1024;
static constexpr size_t O_BMAIN = O_WDF + 16*1024;
static constexpr size_t O_GI1   = O_BMAIN + 1024*4;
static constexpr size_t O_PROBE = O_GI1 + 3072;          // 3x1KB probe sinks

// ---------------- prep kernels (unchanged) ----------------

__global__ void prep_frag(const float* __restrict__ src, __bf16* __restrict__ dst,
                          int SR, int SC, int NF, int NCH) {
  int total = NF * NCH * 512;
  for (int i = blockIdx.x * blockDim.x + threadIdx.x; i < total;
       i += gridDim.x * blockDim.x) {
    int fragid = i >> 9, within = i & 511;
    int lane = within >> 3, j = within & 7;
    int nf = fragid / NCH, kc = fragid - nf * NCH;
    int n = nf * 32 + (lane & 31);
    int k = kc * 16 + (lane >> 5) * 8 + j;
    float v = (n < SR && k < SC) ? src[n * SC + k] : 0.f;
    dst[i] = (__bf16)v;
  }
}

__global__ void prep_st1(const float* __restrict__ Whh, __bf16* __restrict__ dst) {
  int total = 8 * 16 * 3 * 512;
  for (int i = blockIdx.x * blockDim.x + threadIdx.x; i < total;
       i += gridDim.x * blockDim.x) {
    int j = i & 7, lane = (i >> 3) & 63;
    int slice = i >> 9;
    int g = slice % 3, kc = (slice / 3) & 15, w = slice / 48;
    int n = g * 256 + w * 32 + (lane & 31);
    int k = kc * 16 + (lane >> 5) * 8 + j;
    dst[i] = (__bf16)Whh[n * 256 + k];
  }
}

__global__ void prep_main(const float* __restrict__ Whh, const float* __restrict__ Wih,
                          const float* __restrict__ Wd, __bf16* __restrict__ dst) {
  int total = 8 * 16 * 4 * 512;
  for (int i = blockIdx.x * blockDim.x + threadIdx.x; i < total;
       i += gridDim.x * blockDim.x) {
    int j = i & 7, lane = (i >> 3) & 63;
    int slice = i >> 9;
    int g = slice & 3, kc = (slice >> 2) & 15, w = slice >> 6;
    int k = kc * 16 + (lane >> 5) * 8 + j;
    int n = g * 256 + w * 32 + (lane & 31);
    float v = 0.f;
    if (n < 768) v = Whh[n * 256 + k];
    if (n < 512 || n >= 768) {
      int nn = (n < 512) ? n : (n - 256);
      float d = 0.f;
      #pragma unroll
      for (int q = 0; q < A_DIM; ++q) d += Wih[nn * A_DIM + q] * Wd[q * 256 + k];
      v += d;
    }
    dst[i] = (__bf16)v;
  }
}

__global__ void prep_bias(const float* __restrict__ Wih, const float* __restrict__ bih,
                          const float* __restrict__ bhh, const float* __restrict__ bd,
                          float* __restrict__ bmain, float* __restrict__ gi1c) {
  int i = blockIdx.x * blockDim.x + threadIdx.x;
  if (i < 1024) {
    float bm;
    if (i < 512) {
      float d = 0.f;
      #pragma unroll
      for (int q = 0; q < A_DIM; ++q) d += Wih[i * A_DIM + q] * bd[q];
      bm = bhh[i] + bih[i] + d;
    } else if (i < 768) {
      bm = bhh[i];
    } else {
      int nn = i - 256;
      float d = 0.f;
      #pragma unroll
      for (int q = 0; q < A_DIM; ++q) d += Wih[nn * A_DIM + q] * bd[q];
      bm = bih[nn] + d;
    }
    bmain[i] = bm;
  }
  if (i < 768) {
    float s = 32.f * Wih[i * A_DIM + 0];
    #pragma unroll
    for (int q = 1; q < A_DIM; ++q) s -= 32.f * Wih[i * A_DIM + q];
    gi1c[i] = s + bih[i];
  }
}

// ---------------- device helpers ----------------

__device__ __forceinline__ void gload16(const void* g, void* l) {
  __builtin_amdgcn_global_load_lds((const __attribute__((address_space(1))) void*)g,
                                   (__attribute__((address_space(3))) void*)l, 16, 0, 0);
}

__device__ __forceinline__ bf16x8 lds_frag(const __bf16* base, int rowBytes,
                                           int row, int kb) {
  return *(const bf16x8*)((const char*)base + row * rowBytes +
                          (kb ^ ((row & 7) << 4)));
}

__device__ __forceinline__ void gru_gate(const f32x16& ar, const f32x16& az,
                                         const f32x16& ah, const f32x16& ai,
                                         f32x16& hr) {
  #pragma unroll
  for (int g = 0; g < 16; ++g) {
    float r = __builtin_amdgcn_rcpf(1.f + __builtin_amdgcn_exp2f(ar[g] * -1.442695041f));
    float z = __builtin_amdgcn_rcpf(1.f + __builtin_amdgcn_exp2f(az[g] * -1.442695041f));
    float pre = ai[g] + r * ah[g];
    float e = __builtin_amdgcn_exp2f(pre * 2.885390082f);
    float n = 1.f - 2.f * __builtin_amdgcn_rcpf(e + 1.f);
    hr[g] = n + z * (hr[g] - n);
  }
}

__device__ __forceinline__ void write_h(__bf16* hl, int c, int hfv,
                                        const f32x16& hr0, const f32x16& hr1) {
  #pragma unroll
  for (int g = 0; g < 16; ++g) {
    int pat = (g & 3) + 8 * (g >> 2) + 4 * hfv;
    int sw = (2 * c) ^ ((pat & 7) << 4);
    *(__bf16*)((char*)hl + pat * 512 + sw)        = (__bf16)hr0[g];
    *(__bf16*)((char*)hl + (32 + pat) * 512 + sw) = (__bf16)hr1[g];
  }
}

// ---------------- PROBES ----------------

// P1: exact weight stream (shared bytes), nothing else. 4x38 steps.
__global__ __launch_bounds__(512, 2) void probe_load_shared(
    const __bf16* __restrict__ Wmn, float* __restrict__ pout) {
  const int tid = threadIdx.x, w = tid >> 6, l = tid & 63;
  const int ph = (blockIdx.x >> 3) & 15;
  const char* sW = (const char*)Wmn + w * 65536 + (size_t)l * 16;
  int ax = 1, ay = 2, az = 3, aw = 4;
  #pragma unroll 1
  for (int rep = 0; rep < 4; ++rep) {
    #pragma unroll 1
    for (int t = 0; t < 38; ++t) {
      #pragma unroll 4
      for (int kc = 0; kc < 16; ++kc) {
        const char* p = sW + (size_t)(((kc + t + ph) & 15) * 4096);
        int4 a = *(const int4*)p;
        int4 b = *(const int4*)(p + 1024);
        int4 c = *(const int4*)(p + 2048);
        int4 d = *(const int4*)(p + 3072);
        ax ^= a.x ^ b.x ^ c.x ^ d.x;  ay ^= a.y ^ b.y ^ c.y ^ d.y;
        az ^= a.z ^ b.z ^ c.z ^ d.z;  aw ^= a.w ^ b.w ^ c.w ^ d.w;
      }
    }
  }
  asm volatile("" :: "v"(ax), "v"(ay), "v"(az), "v"(aw));
  if (tid == 0) pout[blockIdx.x & 255] = 1.f;
}

// P2: same shape/volume, per-block PRIVATE bytes (read from y region).
__global__ __launch_bounds__(512, 2) void probe_load_distinct(
    const char* __restrict__ src, float* __restrict__ pout) {
  const int tid = threadIdx.x, w = tid >> 6, l = tid & 63;
  const char* base = src + (size_t)blockIdx.x * 208896 + (size_t)l * 16;
  int ax = 1, ay = 2, az = 3, aw = 4;
  #pragma unroll 1
  for (int rep = 0; rep < 4; ++rep) {
    #pragma unroll 1
    for (int t = 0; t < 38; ++t) {
      #pragma unroll 4
      for (int kc = 0; kc < 16; ++kc) {
        int idx = (w * 19 + kc * 3 + t * 7) % 51;
        const char* p = base + (size_t)idx * 4096;
        int4 a = *(const int4*)p;
        int4 b = *(const int4*)(p + 1024);
        int4 c = *(const int4*)(p + 2048);
        int4 d = *(const int4*)(p + 3072);
        ax ^= a.x ^ b.x ^ c.x ^ d.x;  ay ^= a.y ^ b.y ^ c.y ^ d.y;
        az ^= a.z ^ b.z ^ c.z ^ d.z;  aw ^= a.w ^ b.w ^ c.w ^ d.w;
      }
    }
  }
  asm volatile("" :: "v"(ax), "v"(ay), "v"(az), "v"(aw));
  if (tid == 0) pout[blockIdx.x & 255] = 1.f;
}

// P3: full step skeleton, ZERO global loads in the loop (weights pinned).
__global__ __launch_bounds__(512, 2) void probe_skel(
    const __bf16* __restrict__ Wmn, const __bf16* __restrict__ Wdf,
    const float* __restrict__ bmain, float* __restrict__ pout) {
  __shared__ __attribute__((aligned(16))) __bf16 h_lds[64 * 256];
  __shared__ __attribute__((aligned(16))) char wd_lds[16 * 1024];
  __shared__ float pred_lds[64 * A_DIM];
  const int tid = threadIdx.x, w = tid >> 6, l = tid & 63;
  const int lc = l & 31, hfv = l >> 5, c = w * 32 + lc;

  {  // wd + h init
    bf16x8 v0 = *(const bf16x8*)((const char*)Wdf + (w * 2 + 0) * 1024 + (size_t)l * 16);
    bf16x8 v1 = *(const bf16x8*)((const char*)Wdf + (w * 2 + 1) * 1024 + (size_t)l * 16);
    *(bf16x8*)(wd_lds + (w * 2 + 0) * 1024 + (size_t)l * 16) = v0;
    *(bf16x8*)(wd_lds + (w * 2 + 1) * 1024 + (size_t)l * 16) = v1;
  }
  f32x16 hr0, hr1;
  #pragma unroll
  for (int i = 0; i < 16; ++i) { hr0[i] = 0.03f; hr1[i] = -0.02f; }
  write_h(h_lds, c, hfv, hr0, hr1);

  const char* sW = (const char*)Wmn + w * 65536 + (size_t)l * 16;
  bf16x8 wr = *(const bf16x8*)(sW);
  bf16x8 wz = *(const bf16x8*)(sW + 1024);
  bf16x8 wh = *(const bf16x8*)(sW + 2048);
  bf16x8 wi = *(const bf16x8*)(sW + 3072);
  const float i_rm = bmain[c], i_zm = bmain[256 + c];
  const float i_hm = bmain[512 + c], i_nm = bmain[768 + c];
  __syncthreads();

  f32x16 aR0, aR1, aZ0, aZ1, aH0, aH1, aI0, aI1, pacc;
  #pragma unroll 1
  for (int rep = 0; rep < 4; ++rep) {
    #pragma unroll 1
    for (int t = 2; t <= 39; ++t) {
      #pragma unroll
      for (int i = 0; i < 16; ++i) {
        aR0[i] = i_rm; aR1[i] = i_rm; aZ0[i] = i_zm; aZ1[i] = i_zm;
        aH0[i] = i_hm; aH1[i] = i_hm; aI0[i] = i_nm; aI1[i] = i_nm;
        pacc[i] = 0.f;
      }
      #pragma unroll
      for (int kc = 0; kc < 16; ++kc) {
        bf16x8 a0 = lds_frag(h_lds, 512, lc, kc * 32 + hfv * 16);
        bf16x8 a1 = lds_frag(h_lds, 512, 32 + lc, kc * 32 + hfv * 16);
        aR0 = MFMA32(a0, wr, aR0); aR1 = MFMA32(a1, wr, aR1);
        aZ0 = MFMA32(a0, wz, aZ0); aZ1 = MFMA32(a1, wz, aZ1);
        aH0 = MFMA32(a0, wh, aH0); aH1 = MFMA32(a1, wh, aH1);
        aI0 = MFMA32(a0, wi, aI0); aI1 = MFMA32(a1, wi, aI1);
        if (w < 2) {
          bf16x8 bp = *(const bf16x8*)(wd_lds + kc * 1024 + (size_t)l * 16);
          pacc = MFMA32(w ? a1 : a0, bp, pacc);
        }
      }
      if (w < 2 && lc < A_DIM) {
        #pragma unroll
        for (int g = 0; g < 16; ++g) {
          int pat = (g & 3) + 8 * (g >> 2) + 4 * hfv;
          pred_lds[(32 * w + pat) * A_DIM + lc] = pacc[g];
        }
      }
      gru_gate(aR0, aZ0, aH0, aI0, hr0);
      gru_gate(aR1, aZ1, aH1, aI1, hr1);
      __syncthreads();
      write_h(h_lds, c, hfv, hr0, hr1);
      __syncthreads();
    }
  }
  float s = 0.f;
  #pragma unroll
  for (int i = 0; i < 16; ++i) s += hr0[i] + hr1[i];
  s += pred_lds[tid % (64 * A_DIM)];
  asm volatile("" :: "v"(s));
  if (tid == 0) pout[blockIdx.x & 255] = s;
}

// ---------------- main persistent kernel (EXACT v4) ----------------
__global__ __launch_bounds__(512, 2) void decoder_main(
    const float* __restrict__ latent, const float* __restrict__ b1,
    const float* __restrict__ b2, const float* __restrict__ bhh,
    const float* __restrict__ bd, const float* __restrict__ gi1c,
    const float* __restrict__ bmain,
    const __bf16* __restrict__ W1f, const __bf16* __restrict__ W2f,
    const __bf16* __restrict__ St1, const __bf16* __restrict__ Wmn,
    const __bf16* __restrict__ Wdf, float* __restrict__ y) {
  __shared__ __attribute__((aligned(16))) __bf16 h_lds[64 * 256];
  __shared__ __attribute__((aligned(16))) char wd_lds[16 * 1024];
  __shared__ __attribute__((aligned(16))) char ringmem[8 * 3 * 4096];

  const int tid = threadIdx.x;
  const int w = tid >> 6;
  const int l = tid & 63;
  const int lc = l & 31;
  const int hfv = l >> 5;
  const int b0 = blockIdx.x * 64;
  const int c = w * 32 + lc;
  const int ph = (blockIdx.x >> 3) & 15;

  __bf16* lat_al = (__bf16*)(ringmem);
  __bf16* h1_al  = (__bf16*)(ringmem + 16384);

  for (int i = tid; i < 64 * A_DIM; i += 512) {
    int r = i / A_DIM, a = i - r * A_DIM;
    y[(size_t)(b0 + r) * 840 + a] = (a == 0) ? 32.f : -32.f;
  }

  for (int i = tid; i < 64 * 32; i += 512) {
    int r = i >> 5, c4 = i & 31;
    const float4 v = *(const float4*)(latent + (size_t)(b0 + r) * 128 + c4 * 4);
    __bf16* q = (__bf16*)((char*)lat_al + r * 256 + ((c4 * 8) ^ ((r & 7) << 4)));
    q[0] = (__bf16)v.x; q[1] = (__bf16)v.y; q[2] = (__bf16)v.z; q[3] = (__bf16)v.w;
  }
  __syncthreads();

  const bf16x8* W1v = (const bf16x8*)W1f;
  const bf16x8* W2v = (const bf16x8*)W2f;

  f32x16 acc0, acc1;
  {
    const float bb = b1[c];
    #pragma unroll
    for (int i = 0; i < 16; ++i) { acc0[i] = bb; acc1[i] = bb; }
  }
  #pragma unroll
  for (int kc = 0; kc < 8; ++kc) {
    bf16x8 a0 = lds_frag(lat_al, 256, lc, kc * 32 + hfv * 16);
    bf16x8 a1 = lds_frag(lat_al, 256, 32 + lc, kc * 32 + hfv * 16);
    bf16x8 bw = W1v[(w * 8 + kc) * 64 + l];
    acc0 = MFMA32(a0, bw, acc0);
    acc1 = MFMA32(a1, bw, acc1);
  }
  #pragma unroll
  for (int g = 0; g < 16; ++g) {
    int pat = (g & 3) + 8 * (g >> 2) + 4 * hfv;
    int sw = (2 * c) ^ ((pat & 7) << 4);
    float v0 = acc0[g] > 0.f ? acc0[g] : 0.f;
    float v1 = acc1[g] > 0.f ? acc1[g] : 0.f;
    *(__bf16*)((char*)h1_al + pat * 512 + sw)        = (__bf16)v0;
    *(__bf16*)((char*)h1_al + (32 + pat) * 512 + sw) = (__bf16)v1;
  }
  __syncthreads();

  f32x16 hr0, hr1;
  {
    const float bb = b2[c];
    #pragma unroll
    for (int i = 0; i < 16; ++i) { hr0[i] = bb; hr1[i] = bb; }
  }
  #pragma unroll
  for (int kc = 0; kc < 16; ++kc) {
    bf16x8 a0 = lds_frag(h1_al, 512, lc, kc * 32 + hfv * 16);
    bf16x8 a1 = lds_frag(h1_al, 512, 32 + lc, kc * 32 + hfv * 16);
    bf16x8 bw = W2v[(w * 16 + kc) * 64 + l];
    hr0 = MFMA32(a0, bw, hr0);
    hr1 = MFMA32(a1, bw, hr1);
  }
  write_h(h_lds, c, hfv, hr0, hr1);
  __syncthreads();

  const float i_r1 = bhh[c] + gi1c[c];
  const float i_z1 = bhh[256 + c] + gi1c[256 + c];
  const float i_h1 = bhh[512 + c];
  const float i_n1 = gi1c[512 + c];
  const float i_rm = bmain[c];
  const float i_zm = bmain[256 + c];
  const float i_hm = bmain[512 + c];
  const float i_nm = bmain[768 + c];
  const float pb = (lc < A_DIM) ? bd[lc] : 0.f;

  char* ringw = ringmem + w * 12288;
  const char* sW1 = (const char*)St1 + w * 49152 + (size_t)l * 16;
  const char* sW  = (const char*)Wmn + w * 65536 + (size_t)l * 16;

  gload16((const char*)Wdf + (w * 2 + 0) * 1024 + (size_t)l * 16, wd_lds + (w * 2 + 0) * 1024);
  gload16((const char*)Wdf + (w * 2 + 1) * 1024 + (size_t)l * 16, wd_lds + (w * 2 + 1) * 1024);

  f32x16 aR0, aR1, aZ0, aZ1, aH0, aH1, aI0, aI1, pacc;

  #pragma unroll
  for (int p = 0; p < 2; ++p)
    #pragma unroll
    for (int g = 0; g < 3; ++g)
      gload16(sW1 + ((p + ph) & 15) * 3072 + g * 1024, ringw + p * 4096 + g * 1024);

  #pragma unroll
  for (int i = 0; i < 16; ++i) {
    aR0[i] = i_r1; aR1[i] = i_r1; aZ0[i] = i_z1; aZ1[i] = i_z1;
    aH0[i] = i_h1; aH1[i] = i_h1; aI0[i] = i_n1; aI1[i] = i_n1;
  }
  #pragma unroll
  for (int kc = 0; kc < 16; ++kc) {
    const int kcp = (kc + ph) & 15;
    if (kc < 14) {
      const int fi = (kc + 2) % 3;
      const int kcp2 = (kc + 2 + ph) & 15;
      #pragma unroll
      for (int g = 0; g < 3; ++g)
        gload16(sW1 + kcp2 * 3072 + g * 1024, ringw + fi * 4096 + g * 1024);
    }
    if (kc < 14) { WAITV(6); } else if (kc == 14) { WAITV(3); } else { WAITV(0); }
    const char* fc = ringw + (kc % 3) * 4096 + (size_t)l * 16;
    bf16x8 a0 = lds_frag(h_lds, 512, lc, kcp * 32 + hfv * 16);
    bf16x8 a1 = lds_frag(h_lds, 512, 32 + lc, kcp * 32 + hfv * 16);
    bf16x8 br = *(const bf16x8*)(fc);
    bf16x8 bz = *(const bf16x8*)(fc + 1024);
    bf16x8 bh = *(const bf16x8*)(fc + 2048);
    aR0 = MFMA32(a0, br, aR0); aR1 = MFMA32(a1, br, aR1);
    aZ0 = MFMA32(a0, bz, aZ0); aZ1 = MFMA32(a1, bz, aZ1);
    aH0 = MFMA32(a0, bh, aH0); aH1 = MFMA32(a1, bh, aH1);
  }

  #pragma unroll
  for (int p = 0; p < 2; ++p) {
    const char* gsrc = sW + ((p + ph) & 15) * 4096;
    char* fd = ringw + p * 4096;
    gload16(gsrc,        fd);
    gload16(gsrc + 1024, fd + 1024);
    gload16(gsrc + 2048, fd + 2048);
    gload16(gsrc + 3072, fd + 3072);
  }

  gru_gate(aR0, aZ0, aH0, aI0, hr0);
  gru_gate(aR1, aZ1, aH1, aI1, hr1);
  LGKM0(); BARRIER();
  write_h(h_lds, c, hfv, hr0, hr1);
  LGKM0(); BARRIER();

  int base = 0;
  #pragma unroll 1
  for (int t = 2; t <= 39; ++t) {
    #pragma unroll
    for (int i = 0; i < 16; ++i) {
      aR0[i] = i_rm; aR1[i] = i_rm; aZ0[i] = i_zm; aZ1[i] = i_zm;
      aH0[i] = i_hm; aH1[i] = i_hm; aI0[i] = i_nm; aI1[i] = i_nm;
      pacc[i] = pb;
    }
    #pragma unroll
    for (int kc = 0; kc < 16; ++kc) {
      const int kcp = (kc + ph) & 15;
      {
        int f2 = (kc + 2) % 3 + base; if (f2 >= 3) f2 -= 3;
        const char* gsrc = sW + ((kc + 2 + ph) & 15) * 4096;
        char* fd = ringw + f2 * 4096;
        gload16(gsrc,        fd);
        gload16(gsrc + 1024, fd + 1024);
        gload16(gsrc + 2048, fd + 2048);
        gload16(gsrc + 3072, fd + 3072);
      }
      WAITV(8);
      int f0i = kc % 3 + base; if (f0i >= 3) f0i -= 3;
      const char* fc = ringw + f0i * 4096 + (size_t)l * 16;
      bf16x8 a0 = lds_frag(h_lds, 512, lc, kcp * 32 + hfv * 16);
      bf16x8 a1 = lds_frag(h_lds, 512, 32 + lc, kcp * 32 + hfv * 16);
      bf16x8 br = *(const bf16x8*)(fc);
      bf16x8 bz = *(const bf16x8*)(fc + 1024);
      bf16x8 bh = *(const bf16x8*)(fc + 2048);
      bf16x8 bi = *(const bf16x8*)(fc + 3072);
      aR0 = MFMA32(a0, br, aR0); aR1 = MFMA32(a1, br, aR1);
      aZ0 = MFMA32(a0, bz, aZ0); aZ1 = MFMA32(a1, bz, aZ1);
      aH0 = MFMA32(a0, bh, aH0); aH1 = MFMA32(a1, bh, aH1);
      aI0 = MFMA32(a0, bi, aI0); aI1 = MFMA32(a1, bi, aI1);
      if (w < 2) {
        bf16x8 bp = *(const bf16x8*)(wd_lds + kcp * 1024 + (size_t)l * 16);
        pacc = MFMA32(w ? a1 : a0, bp, pacc);
      }
    }
    if (w < 2 && lc < A_DIM) {
      #pragma unroll
      for (int g = 0; g < 16; ++g) {
        int pat = (g & 3) + 8 * (g >> 2) + 4 * hfv;
        y[(size_t)(b0 + 32 * w + pat) * 840 + (size_t)(t - 1) * 21 + lc] = pacc[g];
      }
    }
    gru_gate(aR0, aZ0, aH0, aI0, hr0);
    gru_gate(aR1, aZ1, aH1, aI1, hr1);
    LGKM0(); BARRIER();
    write_h(h_lds, c, hfv, hr0, hr1);
    LGKM0(); BARRIER();
    base = (base == 2) ? 0 : base + 1;
  }

  if (w < 2) {
    #pragma unroll
    for (int i = 0; i < 16; ++i) pacc[i] = pb;
    #pragma unroll
    for (int kc = 0; kc < 16; ++kc) {
      bf16x8 a = lds_frag(h_lds, 512, 32 * w + lc, kc * 32 + hfv * 16);
      bf16x8 bp = *(const bf16x8*)(wd_lds + kc * 1024 + (size_t)l * 16);
      pacc = MFMA32(a, bp, pacc);
    }
    if (lc < A_DIM) {
      #pragma unroll
      for (int g = 0; g < 16; ++g) {
        int pat = (g & 3) + 8 * (g >> 2) + 4 * hfv;
        y[(size_t)(b0 + 32 * w + pat) * 840 + 39 * 21 + lc] = pacc[g];
      }
    }
  }
  WAITV(0);
}

extern "C" void kernel_launch(void* const* d_in, const int* in_sizes, int n_in,
                              void* d_out, int out_size, void* d_ws, size_t ws_size,
                              hipStream_t stream) {
  const float* latent = (const float*)d_in[0];
  const float* W1 = (const float*)d_in[1];
  const float* b1 = (const float*)d_in[2];
  const float* W2 = (const float*)d_in[3];
  const float* b2 = (const float*)d_in[4];
  const float* Wih = (const float*)d_in[5];
  const float* Whh = (const float*)d_in[6];
  const float* bih = (const float*)d_in[7];
  const float* bhh = (const float*)d_in[8];
  const float* Wd = (const float*)d_in[9];
  const float* bd = (const float*)d_in[10];
  float* y = (float*)d_out;
  char* ws = (char*)d_ws;

  __bf16* W1f = (__bf16*)(ws + O_W1F);
  __bf16* W2f = (__bf16*)(ws + O_W2F);
  __bf16* St1 = (__bf16*)(ws + O_ST1);
  __bf16* Wmn = (__bf16*)(ws + O_WMN);
  __bf16* Wdf = (__bf16*)(ws + O_WDF);
  float* bmain = (float*)(ws + O_BMAIN);
  float* gi1c = (float*)(ws + O_GI1);
  float* pout = (float*)(ws + O_PROBE);

  prep_frag<<<128, 256, 0, stream>>>(W1, W1f, 256, 128, 8, 8);
  prep_frag<<<256, 256, 0, stream>>>(W2, W2f, 256, 256, 8, 16);
  prep_frag<<<32, 256, 0, stream>>>(Wd, Wdf, 21, 256, 1, 16);
  prep_st1<<<512, 256, 0, stream>>>(Whh, St1);
  prep_main<<<1024, 256, 0, stream>>>(Whh, Wih, Wd, Wmn);
  prep_bias<<<4, 256, 0, stream>>>(Wih, bih, bhh, bd, bmain, gi1c);

  // ablation probes (timing-only; outputs go to ws scratch)
  probe_load_shared<<<256, 512, 0, stream>>>(Wmn, pout);
  probe_load_distinct<<<256, 512, 0, stream>>>((const char*)y, pout + 256);
  probe_skel<<<256, 512, 0, stream>>>(Wmn, Wdf, bmain, pout + 512);

  decoder_main<<<256, 512, 0, stream>>>(latent, b1, b2, bhh, bd, gi1c, bmain,
                                        W1f, W2f, St1, Wmn, Wdf, y);
}